// Round 18
// baseline (406.979 us; speedup 1.0000x reference)
//
#include <hip/hip_runtime.h>
#include <math.h>

#define N_NODES 20000
#define F_IN    128
#define H_HEADS 5
#define HID     320
#define NHID    512
#define NOUT    256
#define G_GRAPHS 200
#define QROW    160   // int4 table row bytes (320 cols / 2)

typedef __attribute__((ext_vector_type(8))) short bf16x8;
typedef __attribute__((ext_vector_type(4))) float f32x4;
typedef __attribute__((ext_vector_type(4))) unsigned short u16x4;

__device__ __forceinline__ unsigned short f2bf(float f) {
    unsigned int u = __float_as_uint(f);
    u += 0x7fffu + ((u >> 16) & 1u);
    return (unsigned short)(u >> 16);
}
__device__ __forceinline__ float bf2f(unsigned short u) {
    return __uint_as_float(((unsigned int)u) << 16);
}

// ---------------- CSR build (dst -> list of src), self-loops included ----------------
__global__ void k_init_cnt(int* cnt) {
    int i = blockIdx.x * 256 + threadIdx.x;
    if (i < N_NODES) cnt[i] = 1;  // self loop
}

__global__ void k_hist(const int* __restrict__ ei, int* cnt, int E) {
    int e = blockIdx.x * 256 + threadIdx.x;
    if (e < E) atomicAdd(&cnt[ei[E + e]], 1);
}

__global__ __launch_bounds__(1024) void k_scan(const int* __restrict__ cnt, int* off, int* cur) {
    __shared__ int part[1024];
    int t = threadIdx.x;
    const int per = (N_NODES + 1023) / 1024;
    int base = t * per;
    int sum = 0;
    for (int i = 0; i < per; ++i) { int idx = base + i; if (idx < N_NODES) sum += cnt[idx]; }
    part[t] = sum;
    __syncthreads();
    for (int s = 1; s < 1024; s <<= 1) {
        int v = (t >= s) ? part[t - s] : 0;
        __syncthreads();
        part[t] += v;
        __syncthreads();
    }
    int run = (t == 0) ? 0 : part[t - 1];
    for (int i = 0; i < per; ++i) {
        int idx = base + i;
        if (idx < N_NODES) { off[idx] = run; cur[idx] = run; run += cnt[idx]; }
    }
    if (t == 1023) off[N_NODES] = part[1023];
}

// merged self-loop + edge fill
__global__ void k_fill(const int* __restrict__ ei, int* cur, int* srcl, int E) {
    int idx = blockIdx.x * 256 + threadIdx.x;
    if (idx < N_NODES) {
        int p = atomicAdd(&cur[idx], 1);
        srcl[p] = idx;
    } else {
        int e = idx - N_NODES;
        if (e < E) {
            int d = ei[E + e];
            int p = atomicAdd(&cur[d], 1);
            srcl[p] = ei[e];
        }
    }
}

// ---------------- conversions ----------------
__global__ void k_cvt(const float* __restrict__ in, unsigned short* __restrict__ outp, int n) {
    int i = blockIdx.x * 256 + threadIdx.x;
    if (i < n) outp[i] = f2bf(in[i]);
}

// all 7 weight packs in one launch: W [K,320] f32 -> Bp [K/8][320][8] bf16
__global__ void k_wt_all(const float* __restrict__ s0, const float* __restrict__ s1,
                         const float* __restrict__ s2, const float* __restrict__ s3,
                         const float* __restrict__ s4, const float* __restrict__ s5,
                         const float* __restrict__ s6,
                         unsigned short* __restrict__ d0, unsigned short* __restrict__ d1,
                         unsigned short* __restrict__ d2, unsigned short* __restrict__ d3,
                         unsigned short* __restrict__ d4, unsigned short* __restrict__ d5,
                         unsigned short* __restrict__ d6) {
    int y = blockIdx.y;
    const float* S; unsigned short* D; int K;
    switch (y) {
        case 0: S = s0; D = d0; K = F_IN; break;
        case 1: S = s1; D = d1; K = F_IN; break;
        case 2: S = s2; D = d2; K = HID; break;
        case 3: S = s3; D = d3; K = HID; break;
        case 4: S = s4; D = d4; K = HID; break;
        case 5: S = s5; D = d5; K = HID; break;
        default: S = s6; D = d6; K = HID; break;
    }
    int n_elems = HID * K;
    int i = blockIdx.x * 256 + threadIdx.x;
    if (i < n_elems) {
        int kr = i & 7;
        int t  = i >> 3;          // kg*320 + n
        int n  = t % HID;
        int kg = t / HID;
        int k  = kg * 8 + kr;
        D[i] = f2bf(S[(size_t)k * HID + n]);
    }
}

// ---------------- bf16 MFMA GEMM: single-barrier, full-A LDS staging, int4 GAT table ----------------
// QM=32, 256 threads, 4 col-waves. z==0 (GAT): int4 per-row-quantized table (2 cols/byte,
// scale=rowmax/7 in sd slot 5) + packed sd. z==1 (proj): C2 = A@Bp2 + bias2.
#define QM  32

template<int KK>
__global__ __launch_bounds__(256) void k_gemm6(
    const unsigned short* __restrict__ A,
    const unsigned short* __restrict__ Bp,
    unsigned char* __restrict__ Ci4,
    const float* __restrict__ a_s,
    const float* __restrict__ a_d,
    float* __restrict__ sd_out,
    const unsigned short* __restrict__ Bp2,
    const float* __restrict__ bias2,
    float* __restrict__ C2,
    int M)
{
    const bool gat = (blockIdx.z == 0);
    const unsigned short* __restrict__ B = gat ? Bp : Bp2;
    __shared__ unsigned short As[QM][KK + 8];
    __shared__ float sdred[4][2][QM][2];
    __shared__ float maxred[4][QM];
    __shared__ float sinv[QM];
    int tid = threadIdx.x;
    int lane = tid & 63, wid = tid >> 6;
    int wc = wid;
    int q = lane >> 4, r16 = lane & 15;
    int m0 = blockIdx.x * QM;

    const unsigned short* pB[5];
#pragma unroll
    for (int ni = 0; ni < 5; ++ni)
        pB[ni] = B + (size_t)(wc * 80 + ni * 16 + r16) * 8 + (size_t)q * (HID * 8);

    // stage the ENTIRE A tile: coalesced 16B loads, all in flight together
    constexpr int GPR = KK / 8;
    constexpr int NLD = (QM * GPR) / 256;
#pragma unroll
    for (int i = 0; i < NLD; ++i) {
        int idx = tid + i * 256;
        int mrow = idx / GPR, g = idx - mrow * GPR;
        int row = m0 + mrow;
        bf16x8 v;
        if (row < M) v = *(const bf16x8*)(A + (size_t)row * KK + g * 8);
        else { for (int j = 0; j < 8; ++j) v[j] = 0; }
        *(bf16x8*)&As[mrow][g * 8] = v;
    }
    __syncthreads();   // the ONLY barrier before the epilogue

    f32x4 acc[2][5];
#pragma unroll
    for (int mi = 0; mi < 2; ++mi)
#pragma unroll
        for (int ni = 0; ni < 5; ++ni)
#pragma unroll
            for (int r = 0; r < 4; ++r) acc[mi][ni][r] = 0.f;

#pragma unroll
    for (int k0 = 0; k0 < KK; k0 += 32) {
        bf16x8 av[2], bv[5];
#pragma unroll
        for (int mi = 0; mi < 2; ++mi)
            av[mi] = *(const bf16x8*)&As[mi * 16 + r16][k0 + q * 8];
#pragma unroll
        for (int ni = 0; ni < 5; ++ni)
            bv[ni] = *(const bf16x8*)(pB[ni] + (size_t)k0 * HID);
#pragma unroll
        for (int mi = 0; mi < 2; ++mi)
#pragma unroll
            for (int ni = 0; ni < 5; ++ni)
                acc[mi][ni] = __builtin_amdgcn_mfma_f32_16x16x32_bf16(av[mi], bv[ni], acc[mi][ni], 0, 0, 0);
    }

    if (gat) {
        int headA = (5 * wc) >> 2;
#pragma unroll
        for (int mi = 0; mi < 2; ++mi)
#pragma unroll
            for (int r = 0; r < 4; ++r) {
                float psA = 0.f, pdA = 0.f, psB = 0.f, pdB = 0.f, mx = 0.f;
#pragma unroll
                for (int ni = 0; ni < 5; ++ni) {
                    int col = wc * 80 + ni * 16 + r16;
                    int hf = (5 * wc + ni) >> 2;
                    float v = acc[mi][ni][r];
                    float ps = v * a_s[col], pd = v * a_d[col];
                    mx = fmaxf(mx, fabsf(v));
                    if (hf == headA) { psA += ps; pdA += pd; }
                    else             { psB += ps; pdB += pd; }
                }
#pragma unroll
                for (int w = 8; w >= 1; w >>= 1) {
                    psA += __shfl_xor(psA, w, 64);
                    pdA += __shfl_xor(pdA, w, 64);
                    psB += __shfl_xor(psB, w, 64);
                    pdB += __shfl_xor(pdB, w, 64);
                    mx = fmaxf(mx, __shfl_xor(mx, w, 64));
                }
                if (r16 == 0) {
                    int rl = mi * 16 + q * 4 + r;
                    sdred[wc][0][rl][0] = psA; sdred[wc][0][rl][1] = pdA;
                    sdred[wc][1][rl][0] = psB; sdred[wc][1][rl][1] = pdB;
                    maxred[wc][rl] = mx;
                }
            }
        __syncthreads();
        if (tid < QM) {
            int row = m0 + tid;
            if (row < M) {
                float s0 = sdred[0][0][tid][0];
                float s1 = sdred[0][1][tid][0] + sdred[1][0][tid][0];
                float s2 = sdred[1][1][tid][0] + sdred[2][0][tid][0];
                float s3 = sdred[2][1][tid][0] + sdred[3][0][tid][0];
                float s4 = sdred[3][1][tid][0];
                float d0 = sdred[0][0][tid][1];
                float d1 = sdred[0][1][tid][1] + sdred[1][0][tid][1];
                float d2 = sdred[1][1][tid][1] + sdred[2][0][tid][1];
                float d3 = sdred[2][1][tid][1] + sdred[3][0][tid][1];
                float d4 = sdred[3][1][tid][1];
                float mxv = fmaxf(fmaxf(maxred[0][tid], maxred[1][tid]),
                                  fmaxf(maxred[2][tid], maxred[3][tid]));
                mxv = fmaxf(mxv, 1e-20f);
                float scale = mxv * (1.f / 7.f);
                sinv[tid] = 7.f / mxv;
                size_t sb = (size_t)row * 16;
                sd_out[sb + 0] = s0; sd_out[sb + 1] = s1; sd_out[sb + 2] = s2;
                sd_out[sb + 3] = s3; sd_out[sb + 4] = s4;
                sd_out[sb + 5] = scale;
                sd_out[sb + 8] = d0; sd_out[sb + 9] = d1; sd_out[sb + 10] = d2;
                sd_out[sb + 11] = d3; sd_out[sb + 12] = d4;
            }
        }
        __syncthreads();
        // int4 pack: adjacent-column lanes pair via shfl_xor(1); even-r16 lane stores the byte
#pragma unroll
        for (int mi = 0; mi < 2; ++mi)
#pragma unroll
            for (int r = 0; r < 4; ++r) {
                int rl = mi * 16 + q * 4 + r;
                float inv = sinv[rl];
                int row = m0 + rl;
#pragma unroll
                for (int ni = 0; ni < 5; ++ni) {
                    int qv = (int)rintf(acc[mi][ni][r] * inv);
                    qv = max(-7, min(7, qv));
                    int qp = __shfl_xor(qv, 1, 64);
                    if (((r16 & 1) == 0) && row < M) {
                        unsigned char byte = (unsigned char)((qv & 0xF) | ((qp & 0xF) << 4));
                        Ci4[(size_t)row * QROW + 40 * wc + 8 * ni + (r16 >> 1)] = byte;
                    }
                }
            }
    } else {
#pragma unroll
        for (int mi = 0; mi < 2; ++mi)
#pragma unroll
            for (int ni = 0; ni < 5; ++ni) {
                int col = wc * 80 + ni * 16 + r16;
                float bval = bias2[col];
#pragma unroll
                for (int r = 0; r < 4; ++r) {
                    int row = m0 + mi * 16 + q * 4 + r;
                    if (row < M) C2[(size_t)row * HID + col] = acc[mi][ni][r] + bval;
                }
            }
    }
}

// ---------------- GAT aggregation: int4 table (L2-resident 3.2MB), LDS record broadcast ----------------
// 4 waves/block, one node per wave; lane covers cols {4l..4l+3} (1 ushort = 4 nibbles)
// + {256+l} (1 nibble). Per-row scale folded into packed bf16 edge weights; den exact.
__global__ __launch_bounds__(256) void k_agg(const unsigned char* __restrict__ gatq,
                                             const float* __restrict__ sd,
                                             const int* __restrict__ off, const int* __restrict__ srcl,
                                             const float* __restrict__ bias, const float* __restrict__ base,
                                             float* __restrict__ outp, unsigned short* __restrict__ out_bf) {
    __shared__ uint4 rec[4][64];
    int wid = threadIdx.x >> 6;
    int lane = threadIdx.x & 63;
    int i = blockIdx.x * 4 + wid;
    if (i >= N_NODES) return;
    int oS = off[i], oE = off[i + 1];
    int deg = oE - oS;
    const int hsel = lane >> 4;
    const bool lo32 = (lane < 32);

    const float4 dv = *(const float4*)&sd[(size_t)i * 16 + 8];
    const float di4v = sd[(size_t)i * 16 + 12];
    float di[5] = {dv.x, dv.y, dv.z, dv.w, di4v};

    const unsigned char* pa = gatq + 2 * lane;              // bytes for cols 4l..4l+3
    const unsigned char* pc = gatq + 128 + (lane >> 1);     // byte holding col 256+l
    const int nibhi = lane & 1;                             // col 256+l nibble select

    float m[5], den[5] = {0.f, 0.f, 0.f, 0.f, 0.f};
#pragma unroll
    for (int h = 0; h < 5; ++h) m[h] = -1e30f;
    float a0 = 0.f, a1 = 0.f, a2 = 0.f, a3 = 0.f, a4 = 0.f;

    for (int cb = 0; cb < deg; cb += 64) {
        int j = cb + lane;
        bool act = (j < deg);
        int sj = act ? srcl[oS + j] : 0;
        float e[5];
        float scal = 0.f;
        if (act) {
            const float4 sv = *(const float4*)&sd[(size_t)sj * 16];
            const float2 s45 = *(const float2*)&sd[(size_t)sj * 16 + 4];
            scal = s45.y;
            float es0 = sv.x + di[0], es1 = sv.y + di[1], es2 = sv.z + di[2];
            float es3 = sv.w + di[3], es4 = s45.x + di[4];
            e[0] = (es0 >= 0.f) ? es0 : 0.2f * es0;
            e[1] = (es1 >= 0.f) ? es1 : 0.2f * es1;
            e[2] = (es2 >= 0.f) ? es2 : 0.2f * es2;
            e[3] = (es3 >= 0.f) ? es3 : 0.2f * es3;
            e[4] = (es4 >= 0.f) ? es4 : 0.2f * es4;
        } else {
#pragma unroll
            for (int h = 0; h < 5; ++h) e[h] = -1e30f;
        }
        float cm[5];
#pragma unroll
        for (int h = 0; h < 5; ++h) cm[h] = e[h];
#pragma unroll
        for (int w = 32; w >= 1; w >>= 1)
#pragma unroll
            for (int h = 0; h < 5; ++h) cm[h] = fmaxf(cm[h], __shfl_xor(cm[h], w, 64));
        if (cb) {  // online rescale (deg > 64) — practically never taken
            float r[5];
#pragma unroll
            for (int h = 0; h < 5; ++h) {
                float nm = fmaxf(m[h], cm[h]);
                r[h] = __expf(m[h] - nm);
                m[h] = nm;
                den[h] *= r[h];
            }
            float rA = (hsel == 0) ? r[0] : (hsel == 1) ? r[1] : (hsel == 2) ? r[2] : r[3];
            a0 *= rA; a1 *= rA; a2 *= rA; a3 *= rA; a4 *= r[4];
        } else {
#pragma unroll
            for (int h = 0; h < 5; ++h) m[h] = cm[h];
        }
        float ex[5];
#pragma unroll
        for (int h = 0; h < 5; ++h) {
            ex[h] = act ? __expf(e[h] - m[h]) : 0.f;
            den[h] += ex[h];
        }
        uint4 rk;
        rk.x = (unsigned)(sj * QROW);
        rk.y = (unsigned)f2bf(ex[0] * scal) | ((unsigned)f2bf(ex[1] * scal) << 16);
        rk.z = (unsigned)f2bf(ex[2] * scal) | ((unsigned)f2bf(ex[3] * scal) << 16);
        rk.w = (unsigned)f2bf(ex[4] * scal);
        rec[wid][lane] = rk;
        int cnt = min(64, deg - cb);
        for (int jj = 0; jj < cnt; ++jj) {
            uint4 r = rec[wid][jj];
            int o = (int)r.x;
            unsigned wlo = lo32 ? r.y : r.z;
            float wE = bf2f((unsigned short)((hsel & 1) ? (wlo >> 16) : (wlo & 0xffffu)));
            float w4v = bf2f((unsigned short)r.w);
            unsigned short p01 = *(const unsigned short*)(pa + o);
            int b2 = pc[o];
            int b0 = p01 & 0xFF, b1 = p01 >> 8;
            float f0 = (float)(((int)(b0 << 28)) >> 28);
            float f1 = (float)(((int)(b0 << 24)) >> 28);
            float f2v = (float)(((int)(b1 << 28)) >> 28);
            float f3 = (float)(((int)(b1 << 24)) >> 28);
            float f4 = nibhi ? (float)(((int)(b2 << 24)) >> 28)
                             : (float)(((int)(b2 << 28)) >> 28);
            a0 += wE * f0;
            a1 += wE * f1;
            a2 += wE * f2v;
            a3 += wE * f3;
            a4 += w4v * f4;
        }
    }
#pragma unroll
    for (int w = 32; w >= 1; w >>= 1)
#pragma unroll
        for (int h = 0; h < 5; ++h) den[h] += __shfl_xor(den[h], w, 64);

    float dE = (hsel == 0) ? den[0] : (hsel == 1) ? den[1] : (hsel == 2) ? den[2] : den[3];
    int c0i = 4 * lane, c2i = 256 + lane;
    size_t rb = (size_t)i * HID;
    float4 bi0 = *(const float4*)&bias[c0i];
    float  bi2 = bias[c2i];
    float4 ba0 = *(const float4*)&base[rb + c0i];
    float  ba2 = base[rb + c2i];
    float4 o0v;
    o0v.x = ba0.x + fmaxf(a0 / dE + bi0.x, 0.f);
    o0v.y = ba0.y + fmaxf(a1 / dE + bi0.y, 0.f);
    o0v.z = ba0.z + fmaxf(a2 / dE + bi0.z, 0.f);
    o0v.w = ba0.w + fmaxf(a3 / dE + bi0.w, 0.f);
    float o2v = ba2 + fmaxf(a4 / den[4] + bi2, 0.f);
    *(float4*)&outp[rb + c0i] = o0v;
    outp[rb + c2i] = o2v;
    if (out_bf) {
        u16x4 q0;
        q0[0] = f2bf(o0v.x); q0[1] = f2bf(o0v.y);
        q0[2] = f2bf(o0v.z); q0[3] = f2bf(o0v.w);
        *(u16x4*)&out_bf[rb + c0i] = q0;
        out_bf[rb + c2i] = f2bf(o2v);
    }
}

// ---------------- fused pool + MLP1 + MLP2 + LayerNorm (one block per graph) ----------------
__global__ __launch_bounds__(512) void k_mlp(const float* __restrict__ h, const int* __restrict__ batch,
                                             const float* __restrict__ Wh1, const float* __restrict__ bh1,
                                             const float* __restrict__ Wh2, const float* __restrict__ bh2,
                                             const float* __restrict__ g_, const float* __restrict__ beta,
                                             float* __restrict__ outp) {
    __shared__ float pooled[HID];
    __shared__ float z1s[NHID];
    __shared__ float red[NOUT];
    int g = blockIdx.x;
    int t = threadIdx.x;

    int lo = 0, hi = N_NODES;
    while (lo < hi) { int mid = (lo + hi) >> 1; if (batch[mid] < g) lo = mid + 1; else hi = mid; }
    int start = lo;
    hi = N_NODES;
    while (lo < hi) { int mid = (lo + hi) >> 1; if (batch[mid] < g + 1) lo = mid + 1; else hi = mid; }
    int end = lo;

    if (t < HID) {
        float a0 = 0.f, a1 = 0.f, a2 = 0.f, a3 = 0.f;
        int r = start;
        for (; r + 4 <= end; r += 4) {
            a0 += h[(size_t)(r + 0) * HID + t];
            a1 += h[(size_t)(r + 1) * HID + t];
            a2 += h[(size_t)(r + 2) * HID + t];
            a3 += h[(size_t)(r + 3) * HID + t];
        }
        for (; r < end; ++r) a0 += h[(size_t)r * HID + t];
        float acc = (a0 + a1) + (a2 + a3);
        pooled[t] = acc / fmaxf((float)(end - start), 1.f);
    }
    __syncthreads();

    {
        float a0 = bh1[t], a1 = 0.f, a2 = 0.f, a3 = 0.f;
        for (int k = 0; k < HID; k += 4) {
            a0 += pooled[k + 0] * Wh1[(k + 0) * NHID + t];
            a1 += pooled[k + 1] * Wh1[(k + 1) * NHID + t];
            a2 += pooled[k + 2] * Wh1[(k + 2) * NHID + t];
            a3 += pooled[k + 3] * Wh1[(k + 3) * NHID + t];
        }
        z1s[t] = fmaxf((a0 + a1) + (a2 + a3), 0.f);
    }
    __syncthreads();

    int col = t & 255, half = t >> 8;
    float b0 = 0.f, b1 = 0.f, b2 = 0.f, b3 = 0.f;
    int kb = half * 256;
    for (int k = kb; k < kb + 256; k += 4) {
        b0 += z1s[k + 0] * Wh2[(k + 0) * NOUT + col];
        b1 += z1s[k + 1] * Wh2[(k + 1) * NOUT + col];
        b2 += z1s[k + 2] * Wh2[(k + 2) * NOUT + col];
        b3 += z1s[k + 3] * Wh2[(k + 3) * NOUT + col];
    }
    float part = (b0 + b1) + (b2 + b3);
    if (half) red[col] = part;
    __syncthreads();
    float val = 0.f;
    if (!half) val = part + red[col] + bh2[col];
    __syncthreads();
    if (!half) red[col] = val;
    __syncthreads();
    for (int s = 128; s > 0; s >>= 1) { if (t < s) red[t] += red[t + s]; __syncthreads(); }
    float mu = red[0] / (float)NOUT;
    __syncthreads();
    if (!half) { float dvv = val - mu; red[col] = dvv * dvv; }
    __syncthreads();
    for (int s = 128; s > 0; s >>= 1) { if (t < s) red[t] += red[t + s]; __syncthreads(); }
    if (!half) {
        float var = red[0] / (float)NOUT;
        float dvv = val - mu;
        outp[g * NOUT + col] = g_[col] * dvv * rsqrtf(var + 1e-5f) + beta[col];
    }
}

// ---------------- launch ----------------
extern "C" void kernel_launch(void* const* d_in, const int* in_sizes, int n_in,
                              void* d_out, int out_size, void* d_ws, size_t ws_size,
                              hipStream_t stream) {
    const float* x     = (const float*)d_in[0];
    const int*   ei    = (const int*)d_in[1];
    const int*   batch = (const int*)d_in[2];
    const float *W[5], *as_[5], *ad_[5], *bb[5];
    int idx = 3;
    for (int l = 0; l < 5; ++l) {
        W[l]   = (const float*)d_in[idx++];
        as_[l] = (const float*)d_in[idx++];
        ad_[l] = (const float*)d_in[idx++];
        bb[l]  = (const float*)d_in[idx++];
    }
    const float* Wm1 = (const float*)d_in[idx++];
    const float* bm1 = (const float*)d_in[idx++];
    const float* Wm2 = (const float*)d_in[idx++];
    const float* bm2 = (const float*)d_in[idx++];
    const float* Wh1 = (const float*)d_in[idx++];
    const float* bh1 = (const float*)d_in[idx++];
    const float* Wh2 = (const float*)d_in[idx++];
    const float* bh2 = (const float*)d_in[idx++];
    const float* lng = (const float*)d_in[idx++];
    const float* lnb = (const float*)d_in[idx++];

    const int E = in_sizes[1] / 2;
    float* out = (float*)d_out;

    char* ws = (char*)d_ws;
    size_t o = 0;
    auto alloc = [&](size_t bytes) -> char* {
        char* p = ws + o;
        o += bytes;
        o = (o + 255) & ~(size_t)255;
        return p;
    };
    const size_t NB = (size_t)N_NODES * HID * sizeof(float);
    float* big1   = (float*)alloc(NB);
    float* big2   = (float*)alloc(NB);
    float* sdbuf  = (float*)alloc((size_t)N_NODES * 16 * sizeof(float));
    int*   cnt    = (int*)alloc((size_t)N_NODES * sizeof(int));
    int*   off    = (int*)alloc((size_t)(N_NODES + 1) * sizeof(int));
    int*   cur    = (int*)alloc((size_t)N_NODES * sizeof(int));
    int*   srcl   = (int*)alloc((size_t)(E + N_NODES) * sizeof(int));
    unsigned short* x_bf   = (unsigned short*)alloc((size_t)N_NODES * F_IN * sizeof(short));
    unsigned short* h_bf   = (unsigned short*)alloc((size_t)N_NODES * HID * sizeof(short));
    unsigned char*  gat_q  = (unsigned char*)alloc((size_t)N_NODES * QROW);
    unsigned short* Wt1  = (unsigned short*)alloc((size_t)HID * F_IN * sizeof(short));
    unsigned short* Wtm1 = (unsigned short*)alloc((size_t)HID * F_IN * sizeof(short));
    unsigned short* Wt2  = (unsigned short*)alloc((size_t)HID * HID * sizeof(short));
    unsigned short* Wtm2 = (unsigned short*)alloc((size_t)HID * HID * sizeof(short));
    unsigned short* Wt3  = (unsigned short*)alloc((size_t)HID * HID * sizeof(short));
    unsigned short* Wt4  = (unsigned short*)alloc((size_t)HID * HID * sizeof(short));
    unsigned short* Wt5  = (unsigned short*)alloc((size_t)HID * HID * sizeof(short));

    // CSR (4 launches)
    k_init_cnt<<<(N_NODES + 255) / 256, 256, 0, stream>>>(cnt);
    k_hist<<<(E + 255) / 256, 256, 0, stream>>>(ei, cnt, E);
    k_scan<<<1, 1024, 0, stream>>>(cnt, off, cur);
    k_fill<<<(N_NODES + E + 255) / 256, 256, 0, stream>>>(ei, cur, srcl, E);

    // conversions (2 launches)
    {
        int n = N_NODES * F_IN;
        k_cvt<<<(n + 255) / 256, 256, 0, stream>>>(x, x_bf, n);
        dim3 wt_grid((HID * HID + 255) / 256, 7);
        k_wt_all<<<wt_grid, 256, 0, stream>>>(W[0], Wm1, W[1], Wm2, W[2], W[3], W[4],
                                              Wt1, Wtm1, Wt2, Wtm2, Wt3, Wt4, Wt5);
    }

    const int MB = N_NODES / QM;  // 625
    dim3 gg2(MB, 1, 2);
    dim3 gg1(MB, 1, 1);
    const int AGG_B = (N_NODES + 3) / 4;

    // Layer 1
    k_gemm6<F_IN><<<gg2, 256, 0, stream>>>(x_bf, Wt1, gat_q, as_[0], ad_[0], sdbuf,
                                           Wtm1, bm1, big1, N_NODES);
    k_agg<<<AGG_B, 256, 0, stream>>>(gat_q, sdbuf, off, srcl, bb[0], big1, big1, h_bf);

    // Layer 2
    k_gemm6<HID><<<gg2, 256, 0, stream>>>(h_bf, Wt2, gat_q, as_[1], ad_[1], sdbuf,
                                          Wtm2, bm2, big2, N_NODES);
    k_agg<<<AGG_B, 256, 0, stream>>>(gat_q, sdbuf, off, srcl, bb[1], big2, big2, h_bf);

    // Layers 3-5: h = h + relu(gat(h)) in place on big2
    const unsigned short* Wtl[3] = {Wt3, Wt4, Wt5};
    for (int l = 2; l < 5; ++l) {
        k_gemm6<HID><<<gg1, 256, 0, stream>>>(h_bf, Wtl[l - 2], gat_q, as_[l], ad_[l], sdbuf,
                                              nullptr, nullptr, nullptr, N_NODES);
        unsigned short* mirror = (l < 4) ? h_bf : nullptr;
        k_agg<<<AGG_B, 256, 0, stream>>>(gat_q, sdbuf, off, srcl, bb[l], big2, big2, mirror);
    }

    // fused pool + MLP head + LayerNorm (1 launch)
    k_mlp<<<G_GRAPHS, 512, 0, stream>>>(big2, batch, Wh1, bh1, Wh2, bh2, lng, lnb, out);
}

// Round 19
// 374.344 us; speedup vs baseline: 1.0872x; 1.0872x over previous
//
#include <hip/hip_runtime.h>
#include <math.h>

#define N_NODES 20000
#define F_IN    128
#define H_HEADS 5
#define HID     320
#define NHID    512
#define NOUT    256
#define G_GRAPHS 200

typedef __attribute__((ext_vector_type(8))) short bf16x8;
typedef __attribute__((ext_vector_type(4))) float f32x4;
typedef __attribute__((ext_vector_type(4))) unsigned short u16x4;

__device__ __forceinline__ unsigned short f2bf(float f) {
    unsigned int u = __float_as_uint(f);
    u += 0x7fffu + ((u >> 16) & 1u);
    return (unsigned short)(u >> 16);
}
__device__ __forceinline__ float bf2f(unsigned short u) {
    return __uint_as_float(((unsigned int)u) << 16);
}

// ---------------- CSR build (dst -> list of src), self-loops included ----------------
__global__ void k_init_cnt(int* cnt) {
    int i = blockIdx.x * 256 + threadIdx.x;
    if (i < N_NODES) cnt[i] = 1;  // self loop
}

__global__ void k_hist(const int* __restrict__ ei, int* cnt, int E) {
    int e = blockIdx.x * 256 + threadIdx.x;
    if (e < E) atomicAdd(&cnt[ei[E + e]], 1);
}

__global__ __launch_bounds__(1024) void k_scan(const int* __restrict__ cnt, int* off, int* cur) {
    __shared__ int part[1024];
    int t = threadIdx.x;
    const int per = (N_NODES + 1023) / 1024;
    int base = t * per;
    int sum = 0;
    for (int i = 0; i < per; ++i) { int idx = base + i; if (idx < N_NODES) sum += cnt[idx]; }
    part[t] = sum;
    __syncthreads();
    for (int s = 1; s < 1024; s <<= 1) {
        int v = (t >= s) ? part[t - s] : 0;
        __syncthreads();
        part[t] += v;
        __syncthreads();
    }
    int run = (t == 0) ? 0 : part[t - 1];
    for (int i = 0; i < per; ++i) {
        int idx = base + i;
        if (idx < N_NODES) { off[idx] = run; cur[idx] = run; run += cnt[idx]; }
    }
    if (t == 1023) off[N_NODES] = part[1023];
}

// merged self-loop + edge fill
__global__ void k_fill(const int* __restrict__ ei, int* cur, int* srcl, int E) {
    int idx = blockIdx.x * 256 + threadIdx.x;
    if (idx < N_NODES) {
        int p = atomicAdd(&cur[idx], 1);
        srcl[p] = idx;
    } else {
        int e = idx - N_NODES;
        if (e < E) {
            int d = ei[E + e];
            int p = atomicAdd(&cur[d], 1);
            srcl[p] = ei[e];
        }
    }
}

// ---------------- conversions ----------------
__global__ void k_cvt(const float* __restrict__ in, unsigned short* __restrict__ outp, int n) {
    int i = blockIdx.x * 256 + threadIdx.x;
    if (i < n) outp[i] = f2bf(in[i]);
}

// all 7 weight packs in one launch: W [K,320] f32 -> Bp [K/8][320][8] bf16
__global__ void k_wt_all(const float* __restrict__ s0, const float* __restrict__ s1,
                         const float* __restrict__ s2, const float* __restrict__ s3,
                         const float* __restrict__ s4, const float* __restrict__ s5,
                         const float* __restrict__ s6,
                         unsigned short* __restrict__ d0, unsigned short* __restrict__ d1,
                         unsigned short* __restrict__ d2, unsigned short* __restrict__ d3,
                         unsigned short* __restrict__ d4, unsigned short* __restrict__ d5,
                         unsigned short* __restrict__ d6) {
    int y = blockIdx.y;
    const float* S; unsigned short* D; int K;
    switch (y) {
        case 0: S = s0; D = d0; K = F_IN; break;
        case 1: S = s1; D = d1; K = F_IN; break;
        case 2: S = s2; D = d2; K = HID; break;
        case 3: S = s3; D = d3; K = HID; break;
        case 4: S = s4; D = d4; K = HID; break;
        case 5: S = s5; D = d5; K = HID; break;
        default: S = s6; D = d6; K = HID; break;
    }
    int n_elems = HID * K;
    int i = blockIdx.x * 256 + threadIdx.x;
    if (i < n_elems) {
        int kr = i & 7;
        int t  = i >> 3;          // kg*320 + n
        int n  = t % HID;
        int kg = t / HID;
        int k  = kg * 8 + kr;
        D[i] = f2bf(S[(size_t)k * HID + n]);
    }
}

// ---------------- bf16 MFMA GEMM: single-barrier, full-A LDS staging ----------------
// QM=32, 256 threads, 4 col-waves. Whole A tile (32xKK) staged ONCE with overlapped loads,
// one __syncthreads, then the entire K loop runs barrier-free (LDS A + L2-resident packed B).
// Packed-B short-offset for k0 is k0*HID  (Bp[kg][320][8], kg=k/8).
// z==0 (GAT): int8 per-row-quantized table + packed sd. z==1 (proj): C2 = A@Bp2 + bias2.
#define QM  32

template<int KK>
__global__ __launch_bounds__(256) void k_gemm6(
    const unsigned short* __restrict__ A,
    const unsigned short* __restrict__ Bp,
    signed char* __restrict__ Ci8,
    const float* __restrict__ a_s,
    const float* __restrict__ a_d,
    float* __restrict__ sd_out,
    const unsigned short* __restrict__ Bp2,
    const float* __restrict__ bias2,
    float* __restrict__ C2,
    int M)
{
    const bool gat = (blockIdx.z == 0);
    const unsigned short* __restrict__ B = gat ? Bp : Bp2;
    __shared__ unsigned short As[QM][KK + 8];   // +8 shorts: row stride 2-way-conflict-free
    __shared__ float sdred[4][2][QM][2];
    __shared__ float maxred[4][QM];
    __shared__ float sinv[QM];
    int tid = threadIdx.x;
    int lane = tid & 63, wid = tid >> 6;
    int wc = wid;
    int q = lane >> 4, r16 = lane & 15;
    int m0 = blockIdx.x * QM;

    const unsigned short* pB[5];
#pragma unroll
    for (int ni = 0; ni < 5; ++ni)
        pB[ni] = B + (size_t)(wc * 80 + ni * 16 + r16) * 8 + (size_t)q * (HID * 8);

    // stage the ENTIRE A tile: coalesced 16B loads, all in flight together
    constexpr int GPR = KK / 8;                  // 16B-groups per row
    constexpr int NLD = (QM * GPR) / 256;        // loads per thread (2 for K=128, 5 for K=320)
#pragma unroll
    for (int i = 0; i < NLD; ++i) {
        int idx = tid + i * 256;
        int mrow = idx / GPR, g = idx - mrow * GPR;
        int row = m0 + mrow;
        bf16x8 v;
        if (row < M) v = *(const bf16x8*)(A + (size_t)row * KK + g * 8);
        else { for (int j = 0; j < 8; ++j) v[j] = 0; }
        *(bf16x8*)&As[mrow][g * 8] = v;
    }
    __syncthreads();   // the ONLY barrier before the epilogue

    f32x4 acc[2][5];
#pragma unroll
    for (int mi = 0; mi < 2; ++mi)
#pragma unroll
        for (int ni = 0; ni < 5; ++ni)
#pragma unroll
            for (int r = 0; r < 4; ++r) acc[mi][ni][r] = 0.f;

#pragma unroll
    for (int k0 = 0; k0 < KK; k0 += 32) {
        bf16x8 av[2], bv[5];
#pragma unroll
        for (int mi = 0; mi < 2; ++mi)
            av[mi] = *(const bf16x8*)&As[mi * 16 + r16][k0 + q * 8];
#pragma unroll
        for (int ni = 0; ni < 5; ++ni)
            bv[ni] = *(const bf16x8*)(pB[ni] + (size_t)k0 * HID);
#pragma unroll
        for (int mi = 0; mi < 2; ++mi)
#pragma unroll
            for (int ni = 0; ni < 5; ++ni)
                acc[mi][ni] = __builtin_amdgcn_mfma_f32_16x16x32_bf16(av[mi], bv[ni], acc[mi][ni], 0, 0, 0);
    }

    if (gat) {
        int headA = (5 * wc) >> 2;
#pragma unroll
        for (int mi = 0; mi < 2; ++mi)
#pragma unroll
            for (int r = 0; r < 4; ++r) {
                float psA = 0.f, pdA = 0.f, psB = 0.f, pdB = 0.f, mx = 0.f;
#pragma unroll
                for (int ni = 0; ni < 5; ++ni) {
                    int col = wc * 80 + ni * 16 + r16;
                    int hf = (5 * wc + ni) >> 2;
                    float v = acc[mi][ni][r];
                    float ps = v * a_s[col], pd = v * a_d[col];
                    mx = fmaxf(mx, fabsf(v));
                    if (hf == headA) { psA += ps; pdA += pd; }
                    else             { psB += ps; pdB += pd; }
                }
#pragma unroll
                for (int w = 8; w >= 1; w >>= 1) {
                    psA += __shfl_xor(psA, w, 64);
                    pdA += __shfl_xor(pdA, w, 64);
                    psB += __shfl_xor(psB, w, 64);
                    pdB += __shfl_xor(pdB, w, 64);
                    mx = fmaxf(mx, __shfl_xor(mx, w, 64));
                }
                if (r16 == 0) {
                    int rl = mi * 16 + q * 4 + r;
                    sdred[wc][0][rl][0] = psA; sdred[wc][0][rl][1] = pdA;
                    sdred[wc][1][rl][0] = psB; sdred[wc][1][rl][1] = pdB;
                    maxred[wc][rl] = mx;
                }
            }
        __syncthreads();
        if (tid < QM) {
            int row = m0 + tid;
            if (row < M) {
                float s0 = sdred[0][0][tid][0];
                float s1 = sdred[0][1][tid][0] + sdred[1][0][tid][0];
                float s2 = sdred[1][1][tid][0] + sdred[2][0][tid][0];
                float s3 = sdred[2][1][tid][0] + sdred[3][0][tid][0];
                float s4 = sdred[3][1][tid][0];
                float d0 = sdred[0][0][tid][1];
                float d1 = sdred[0][1][tid][1] + sdred[1][0][tid][1];
                float d2 = sdred[1][1][tid][1] + sdred[2][0][tid][1];
                float d3 = sdred[2][1][tid][1] + sdred[3][0][tid][1];
                float d4 = sdred[3][1][tid][1];
                float mxv = fmaxf(fmaxf(maxred[0][tid], maxred[1][tid]),
                                  fmaxf(maxred[2][tid], maxred[3][tid]));
                mxv = fmaxf(mxv, 1e-20f);
                float scale = mxv * (1.f / 127.f);
                sinv[tid] = 127.f / mxv;
                size_t sb = (size_t)row * 16;
                sd_out[sb + 0] = s0; sd_out[sb + 1] = s1; sd_out[sb + 2] = s2;
                sd_out[sb + 3] = s3; sd_out[sb + 4] = s4;
                sd_out[sb + 5] = scale;
                sd_out[sb + 8] = d0; sd_out[sb + 9] = d1; sd_out[sb + 10] = d2;
                sd_out[sb + 11] = d3; sd_out[sb + 12] = d4;
            }
        }
        __syncthreads();
#pragma unroll
        for (int mi = 0; mi < 2; ++mi)
#pragma unroll
            for (int r = 0; r < 4; ++r) {
                int rl = mi * 16 + q * 4 + r;
                float inv = sinv[rl];
                int row = m0 + rl;
                if (row < M) {
#pragma unroll
                    for (int ni = 0; ni < 5; ++ni) {
                        int col = wc * 80 + ni * 16 + r16;
                        int qv = (int)rintf(acc[mi][ni][r] * inv);
                        qv = max(-127, min(127, qv));
                        Ci8[(size_t)row * HID + col] = (signed char)qv;
                    }
                }
            }
    } else {
#pragma unroll
        for (int mi = 0; mi < 2; ++mi)
#pragma unroll
            for (int ni = 0; ni < 5; ++ni) {
                int col = wc * 80 + ni * 16 + r16;
                float bval = bias2[col];
#pragma unroll
                for (int r = 0; r < 4; ++r) {
                    int row = m0 + mi * 16 + q * 4 + r;
                    if (row < M) C2[(size_t)row * HID + col] = acc[mi][ni][r] + bval;
                }
            }
    }
}

// ---------------- GAT aggregation: int8 table, packed LDS record broadcast, 4+1 split ----------------
__global__ __launch_bounds__(256) void k_agg(const signed char* __restrict__ gatq,
                                             const float* __restrict__ sd,
                                             const int* __restrict__ off, const int* __restrict__ srcl,
                                             const float* __restrict__ bias, const float* __restrict__ base,
                                             float* __restrict__ outp, unsigned short* __restrict__ out_bf) {
    __shared__ uint4 rec[4][64];
    int wid = threadIdx.x >> 6;
    int lane = threadIdx.x & 63;
    int i = blockIdx.x * 4 + wid;
    if (i >= N_NODES) return;
    int oS = off[i], oE = off[i + 1];
    int deg = oE - oS;
    const int hsel = lane >> 4;   // which head owns cols 4l..4l+3 (0..3)
    const bool lo32 = (lane < 32);

    const float4 dv = *(const float4*)&sd[(size_t)i * 16 + 8];
    const float di4v = sd[(size_t)i * 16 + 12];
    float di[5] = {dv.x, dv.y, dv.z, dv.w, di4v};

    const signed char* pa = gatq + 4 * lane;        // cols 4l..4l+3
    const signed char* pc = gatq + 256 + lane;      // col 256+l

    float m[5], den[5] = {0.f, 0.f, 0.f, 0.f, 0.f};
#pragma unroll
    for (int h = 0; h < 5; ++h) m[h] = -1e30f;
    float a0 = 0.f, a1 = 0.f, a2 = 0.f, a3 = 0.f, a4 = 0.f;

    for (int cb = 0; cb < deg; cb += 64) {
        int j = cb + lane;
        bool act = (j < deg);
        int sj = act ? srcl[oS + j] : 0;
        float e[5];
        float scal = 0.f;
        if (act) {
            const float4 sv = *(const float4*)&sd[(size_t)sj * 16];
            const float2 s45 = *(const float2*)&sd[(size_t)sj * 16 + 4];
            scal = s45.y;
            float es0 = sv.x + di[0], es1 = sv.y + di[1], es2 = sv.z + di[2];
            float es3 = sv.w + di[3], es4 = s45.x + di[4];
            e[0] = (es0 >= 0.f) ? es0 : 0.2f * es0;
            e[1] = (es1 >= 0.f) ? es1 : 0.2f * es1;
            e[2] = (es2 >= 0.f) ? es2 : 0.2f * es2;
            e[3] = (es3 >= 0.f) ? es3 : 0.2f * es3;
            e[4] = (es4 >= 0.f) ? es4 : 0.2f * es4;
        } else {
#pragma unroll
            for (int h = 0; h < 5; ++h) e[h] = -1e30f;
        }
        float cm[5];
#pragma unroll
        for (int h = 0; h < 5; ++h) cm[h] = e[h];
#pragma unroll
        for (int w = 32; w >= 1; w >>= 1)
#pragma unroll
            for (int h = 0; h < 5; ++h) cm[h] = fmaxf(cm[h], __shfl_xor(cm[h], w, 64));
        if (cb) {  // online rescale (deg > 64) — practically never taken
            float r[5];
#pragma unroll
            for (int h = 0; h < 5; ++h) {
                float nm = fmaxf(m[h], cm[h]);
                r[h] = __expf(m[h] - nm);
                m[h] = nm;
                den[h] *= r[h];
            }
            float rA = (hsel == 0) ? r[0] : (hsel == 1) ? r[1] : (hsel == 2) ? r[2] : r[3];
            a0 *= rA; a1 *= rA; a2 *= rA; a3 *= rA; a4 *= r[4];
        } else {
#pragma unroll
            for (int h = 0; h < 5; ++h) m[h] = cm[h];
        }
        float ex[5];
#pragma unroll
        for (int h = 0; h < 5; ++h) {
            ex[h] = act ? __expf(e[h] - m[h]) : 0.f;
            den[h] += ex[h];
        }
        // pack {byte-offset, 5 x bf16 (weight*scale)}; den stays exact f32
        uint4 rk;
        rk.x = (unsigned)(sj * HID);
        rk.y = (unsigned)f2bf(ex[0] * scal) | ((unsigned)f2bf(ex[1] * scal) << 16);
        rk.z = (unsigned)f2bf(ex[2] * scal) | ((unsigned)f2bf(ex[3] * scal) << 16);
        rk.w = (unsigned)f2bf(ex[4] * scal);
        rec[wid][lane] = rk;
        int cnt = min(64, deg - cb);
        for (int jj = 0; jj < cnt; ++jj) {
            uint4 r = rec[wid][jj];          // uniform address -> LDS broadcast
            int o = (int)r.x;
            unsigned wlo = lo32 ? r.y : r.z;
            float wE = bf2f((unsigned short)((hsel & 1) ? (wlo >> 16) : (wlo & 0xffffu)));
            float w4v = bf2f((unsigned short)r.w);
            char4 p0 = *(const char4*)(pa + o);
            signed char p2v = pc[o];
            a0 += wE * (float)p0.x;
            a1 += wE * (float)p0.y;
            a2 += wE * (float)p0.z;
            a3 += wE * (float)p0.w;
            a4 += w4v * (float)p2v;
        }
    }
#pragma unroll
    for (int w = 32; w >= 1; w >>= 1)
#pragma unroll
        for (int h = 0; h < 5; ++h) den[h] += __shfl_xor(den[h], w, 64);

    float dE = (hsel == 0) ? den[0] : (hsel == 1) ? den[1] : (hsel == 2) ? den[2] : den[3];
    int c0i = 4 * lane, c2i = 256 + lane;
    size_t rb = (size_t)i * HID;
    float4 bi0 = *(const float4*)&bias[c0i];
    float  bi2 = bias[c2i];
    float4 ba0 = *(const float4*)&base[rb + c0i];
    float  ba2 = base[rb + c2i];
    float4 o0v;
    o0v.x = ba0.x + fmaxf(a0 / dE + bi0.x, 0.f);
    o0v.y = ba0.y + fmaxf(a1 / dE + bi0.y, 0.f);
    o0v.z = ba0.z + fmaxf(a2 / dE + bi0.z, 0.f);
    o0v.w = ba0.w + fmaxf(a3 / dE + bi0.w, 0.f);
    float o2v = ba2 + fmaxf(a4 / den[4] + bi2, 0.f);
    *(float4*)&outp[rb + c0i] = o0v;
    outp[rb + c2i] = o2v;
    if (out_bf) {
        u16x4 q0;
        q0[0] = f2bf(o0v.x); q0[1] = f2bf(o0v.y);
        q0[2] = f2bf(o0v.z); q0[3] = f2bf(o0v.w);
        *(u16x4*)&out_bf[rb + c0i] = q0;
        out_bf[rb + c2i] = f2bf(o2v);
    }
}

// ---------------- fused pool + MLP1 + MLP2 + LayerNorm (one block per graph) ----------------
__global__ __launch_bounds__(512) void k_mlp(const float* __restrict__ h, const int* __restrict__ batch,
                                             const float* __restrict__ Wh1, const float* __restrict__ bh1,
                                             const float* __restrict__ Wh2, const float* __restrict__ bh2,
                                             const float* __restrict__ g_, const float* __restrict__ beta,
                                             float* __restrict__ outp) {
    __shared__ float pooled[HID];
    __shared__ float z1s[NHID];
    __shared__ float red[NOUT];
    int g = blockIdx.x;
    int t = threadIdx.x;

    int lo = 0, hi = N_NODES;
    while (lo < hi) { int mid = (lo + hi) >> 1; if (batch[mid] < g) lo = mid + 1; else hi = mid; }
    int start = lo;
    hi = N_NODES;
    while (lo < hi) { int mid = (lo + hi) >> 1; if (batch[mid] < g + 1) lo = mid + 1; else hi = mid; }
    int end = lo;

    if (t < HID) {
        float a0 = 0.f, a1 = 0.f, a2 = 0.f, a3 = 0.f;
        int r = start;
        for (; r + 4 <= end; r += 4) {
            a0 += h[(size_t)(r + 0) * HID + t];
            a1 += h[(size_t)(r + 1) * HID + t];
            a2 += h[(size_t)(r + 2) * HID + t];
            a3 += h[(size_t)(r + 3) * HID + t];
        }
        for (; r < end; ++r) a0 += h[(size_t)r * HID + t];
        float acc = (a0 + a1) + (a2 + a3);
        pooled[t] = acc / fmaxf((float)(end - start), 1.f);
    }
    __syncthreads();

    {
        float a0 = bh1[t], a1 = 0.f, a2 = 0.f, a3 = 0.f;
        for (int k = 0; k < HID; k += 4) {
            a0 += pooled[k + 0] * Wh1[(k + 0) * NHID + t];
            a1 += pooled[k + 1] * Wh1[(k + 1) * NHID + t];
            a2 += pooled[k + 2] * Wh1[(k + 2) * NHID + t];
            a3 += pooled[k + 3] * Wh1[(k + 3) * NHID + t];
        }
        z1s[t] = fmaxf((a0 + a1) + (a2 + a3), 0.f);
    }
    __syncthreads();

    int col = t & 255, half = t >> 8;
    float b0 = 0.f, b1 = 0.f, b2 = 0.f, b3 = 0.f;
    int kb = half * 256;
    for (int k = kb; k < kb + 256; k += 4) {
        b0 += z1s[k + 0] * Wh2[(k + 0) * NOUT + col];
        b1 += z1s[k + 1] * Wh2[(k + 1) * NOUT + col];
        b2 += z1s[k + 2] * Wh2[(k + 2) * NOUT + col];
        b3 += z1s[k + 3] * Wh2[(k + 3) * NOUT + col];
    }
    float part = (b0 + b1) + (b2 + b3);
    if (half) red[col] = part;
    __syncthreads();
    float val = 0.f;
    if (!half) val = part + red[col] + bh2[col];
    __syncthreads();
    if (!half) red[col] = val;
    __syncthreads();
    for (int s = 128; s > 0; s >>= 1) { if (t < s) red[t] += red[t + s]; __syncthreads(); }
    float mu = red[0] / (float)NOUT;
    __syncthreads();
    if (!half) { float dvv = val - mu; red[col] = dvv * dvv; }
    __syncthreads();
    for (int s = 128; s > 0; s >>= 1) { if (t < s) red[t] += red[t + s]; __syncthreads(); }
    if (!half) {
        float var = red[0] / (float)NOUT;
        float dvv = val - mu;
        outp[g * NOUT + col] = g_[col] * dvv * rsqrtf(var + 1e-5f) + beta[col];
    }
}

// ---------------- launch ----------------
extern "C" void kernel_launch(void* const* d_in, const int* in_sizes, int n_in,
                              void* d_out, int out_size, void* d_ws, size_t ws_size,
                              hipStream_t stream) {
    const float* x     = (const float*)d_in[0];
    const int*   ei    = (const int*)d_in[1];
    const int*   batch = (const int*)d_in[2];
    const float *W[5], *as_[5], *ad_[5], *bb[5];
    int idx = 3;
    for (int l = 0; l < 5; ++l) {
        W[l]   = (const float*)d_in[idx++];
        as_[l] = (const float*)d_in[idx++];
        ad_[l] = (const float*)d_in[idx++];
        bb[l]  = (const float*)d_in[idx++];
    }
    const float* Wm1 = (const float*)d_in[idx++];
    const float* bm1 = (const float*)d_in[idx++];
    const float* Wm2 = (const float*)d_in[idx++];
    const float* bm2 = (const float*)d_in[idx++];
    const float* Wh1 = (const float*)d_in[idx++];
    const float* bh1 = (const float*)d_in[idx++];
    const float* Wh2 = (const float*)d_in[idx++];
    const float* bh2 = (const float*)d_in[idx++];
    const float* lng = (const float*)d_in[idx++];
    const float* lnb = (const float*)d_in[idx++];

    const int E = in_sizes[1] / 2;
    float* out = (float*)d_out;

    char* ws = (char*)d_ws;
    size_t o = 0;
    auto alloc = [&](size_t bytes) -> char* {
        char* p = ws + o;
        o += bytes;
        o = (o + 255) & ~(size_t)255;
        return p;
    };
    const size_t NB = (size_t)N_NODES * HID * sizeof(float);
    float* big1   = (float*)alloc(NB);
    float* big2   = (float*)alloc(NB);
    float* sdbuf  = (float*)alloc((size_t)N_NODES * 16 * sizeof(float));
    int*   cnt    = (int*)alloc((size_t)N_NODES * sizeof(int));
    int*   off    = (int*)alloc((size_t)(N_NODES + 1) * sizeof(int));
    int*   cur    = (int*)alloc((size_t)N_NODES * sizeof(int));
    int*   srcl   = (int*)alloc((size_t)(E + N_NODES) * sizeof(int));
    unsigned short* x_bf   = (unsigned short*)alloc((size_t)N_NODES * F_IN * sizeof(short));
    unsigned short* h_bf   = (unsigned short*)alloc((size_t)N_NODES * HID * sizeof(short));
    signed char*    gat_q  = (signed char*)alloc((size_t)N_NODES * HID);
    unsigned short* Wt1  = (unsigned short*)alloc((size_t)HID * F_IN * sizeof(short));
    unsigned short* Wtm1 = (unsigned short*)alloc((size_t)HID * F_IN * sizeof(short));
    unsigned short* Wt2  = (unsigned short*)alloc((size_t)HID * HID * sizeof(short));
    unsigned short* Wtm2 = (unsigned short*)alloc((size_t)HID * HID * sizeof(short));
    unsigned short* Wt3  = (unsigned short*)alloc((size_t)HID * HID * sizeof(short));
    unsigned short* Wt4  = (unsigned short*)alloc((size_t)HID * HID * sizeof(short));
    unsigned short* Wt5  = (unsigned short*)alloc((size_t)HID * HID * sizeof(short));

    // CSR (4 launches)
    k_init_cnt<<<(N_NODES + 255) / 256, 256, 0, stream>>>(cnt);
    k_hist<<<(E + 255) / 256, 256, 0, stream>>>(ei, cnt, E);
    k_scan<<<1, 1024, 0, stream>>>(cnt, off, cur);
    k_fill<<<(N_NODES + E + 255) / 256, 256, 0, stream>>>(ei, cur, srcl, E);

    // conversions (2 launches)
    {
        int n = N_NODES * F_IN;
        k_cvt<<<(n + 255) / 256, 256, 0, stream>>>(x, x_bf, n);
        dim3 wt_grid((HID * HID + 255) / 256, 7);
        k_wt_all<<<wt_grid, 256, 0, stream>>>(W[0], Wm1, W[1], Wm2, W[2], W[3], W[4],
                                              Wt1, Wtm1, Wt2, Wtm2, Wt3, Wt4, Wt5);
    }

    const int MB = N_NODES / QM;  // 625
    dim3 gg2(MB, 1, 2);
    dim3 gg1(MB, 1, 1);
    const int AGG_B = (N_NODES + 3) / 4;

    // Layer 1
    k_gemm6<F_IN><<<gg2, 256, 0, stream>>>(x_bf, Wt1, gat_q, as_[0], ad_[0], sdbuf,
                                           Wtm1, bm1, big1, N_NODES);
    k_agg<<<AGG_B, 256, 0, stream>>>(gat_q, sdbuf, off, srcl, bb[0], big1, big1, h_bf);

    // Layer 2
    k_gemm6<HID><<<gg2, 256, 0, stream>>>(h_bf, Wt2, gat_q, as_[1], ad_[1], sdbuf,
                                          Wtm2, bm2, big2, N_NODES);
    k_agg<<<AGG_B, 256, 0, stream>>>(gat_q, sdbuf, off, srcl, bb[1], big2, big2, h_bf);

    // Layers 3-5: h = h + relu(gat(h)) in place on big2
    const unsigned short* Wtl[3] = {Wt3, Wt4, Wt5};
    for (int l = 2; l < 5; ++l) {
        k_gemm6<HID><<<gg1, 256, 0, stream>>>(h_bf, Wtl[l - 2], gat_q, as_[l], ad_[l], sdbuf,
                                              nullptr, nullptr, nullptr, N_NODES);
        unsigned short* mirror = (l < 4) ? h_bf : nullptr;
        k_agg<<<AGG_B, 256, 0, stream>>>(gat_q, sdbuf, off, srcl, bb[l], big2, big2, mirror);
    }

    // fused pool + MLP head + LayerNorm (1 launch)
    k_mlp<<<G_GRAPHS, 512, 0, stream>>>(big2, batch, Wh1, bh1, Wh2, bh2, lng, lnb, out);
}